// Round 3
// baseline (29877.316 us; speedup 1.0000x reference)
//
#include <hip/hip_runtime.h>
#include <stdint.h>

// PolicyNetRSNNPB R3: cooperative column-sharded design.
// 256 blocks (1/CU), block j owns 8 columns of both hidden layers; weight
// column-slices (Vr, Wf) live in LDS (128 KB). Thread t carries sample t's
// state for those columns in registers. Spikes exchanged via global mask
// arrays (bytes -> crew-packed words), 2 grid barriers/step.
// All FP add orders replicate R1 (bit-exact, absmax was 0.0).

#define NB 512
#define HD 2048
#define NSTEPS 128
#define NBLK 256
#define THREADS 512
#define C 8
#define KS 8
#define NW 32   // 64-bit mask words per sample

// ---- ws layout (bytes) ----
#define OFF_M1B 0         // u8 [256][512]
#define OFF_M2B 131072    // u8 [256][512]
#define OFF_M1W 262144    // u64 [32][512]
#define OFF_M2W 393216    // u64 [32][512]
#define OFF_CNT 524288    // unsigned
#define OFF_GEN 524292    // unsigned

__global__ void init_ws_kernel(unsigned long long* __restrict__ m1W,
                               unsigned* __restrict__ cnt,
                               unsigned* __restrict__ gen) {
  int i = blockIdx.x * 256 + threadIdx.x;
  if (i < NW * NB) m1W[i] = 0ULL;
  if (i == 0) { *cnt = 0u; *gen = 0u; }
}

// sense-reversal grid barrier. Spin loads MUST be agent-scope atomics:
// a plain/volatile load can spin forever on a stale per-XCD L2 line.
__device__ __forceinline__ void gridbar(unsigned* cnt, unsigned* gen) {
  __syncthreads();   // drains this block's outstanding stores (vmcnt 0)
  if (threadIdx.x == 0) {
    __threadfence(); // release: flush dirty L2 to coherent point
    unsigned g = __hip_atomic_load(gen, __ATOMIC_RELAXED, __HIP_MEMORY_SCOPE_AGENT);
    if (atomicAdd(cnt, 1u) == NBLK - 1) {
      __hip_atomic_store(cnt, 0u, __ATOMIC_RELAXED, __HIP_MEMORY_SCOPE_AGENT);
      __threadfence();
      atomicAdd(gen, 1u);
    } else {
      while (__hip_atomic_load(gen, __ATOMIC_RELAXED, __HIP_MEMORY_SCOPE_AGENT) == g)
        __builtin_amdgcn_s_sleep(2);
    }
    __threadfence(); // acquire: invalidate stale cached lines
  }
  __syncthreads();
}

// acc[c] += W_s[k][c] over spikes k of sample `tid`, ascending k (bit-exact
// order). Mask words streamed with an 8-deep ring; weight rows 2-stage
// prefetched from LDS.
__device__ __forceinline__ void gather8(const float* __restrict__ Ws,
                                        const unsigned long long* __restrict__ mp,
                                        int tid, float* acc) {
  unsigned long long ring[8];
#pragma unroll
  for (int q = 0; q < 8; ++q) ring[q] = mp[q * NB + tid];
  int w = -1;
  unsigned long long cur = 0ULL;
  int kA = -1;
  while (true) {
    if (cur == 0ULL) {
      ++w; if (w >= NW) break;
      cur = ring[w & 7];
      int wn = w + 8; if (wn < NW) ring[w & 7] = mp[wn * NB + tid];
      continue;
    }
    kA = (w << 6) + __builtin_ctzll(cur); cur &= cur - 1; break;
  }
  if (kA < 0) return;
  float4 loA = *(const float4*)&Ws[kA * C];
  float4 hiA = *(const float4*)&Ws[kA * C + 4];
  while (true) {
    int kB = -1;
    while (true) {
      if (cur == 0ULL) {
        ++w; if (w >= NW) break;
        cur = ring[w & 7];
        int wn = w + 8; if (wn < NW) ring[w & 7] = mp[wn * NB + tid];
        continue;
      }
      kB = (w << 6) + __builtin_ctzll(cur); cur &= cur - 1; break;
    }
    float4 loB = make_float4(0.f, 0.f, 0.f, 0.f);
    float4 hiB = make_float4(0.f, 0.f, 0.f, 0.f);
    if (kB >= 0) {
      loB = *(const float4*)&Ws[kB * C];
      hiB = *(const float4*)&Ws[kB * C + 4];
    }
    acc[0] += loA.x; acc[1] += loA.y; acc[2] += loA.z; acc[3] += loA.w;
    acc[4] += hiA.x; acc[5] += hiA.y; acc[6] += hiA.z; acc[7] += hiA.w;
    if (kB < 0) return;
    loA = loB; hiA = hiB;
  }
}

// serial ascending readout walk: a += Wo[k][col] over spikes k of `sample`.
__device__ __forceinline__ float rowalk(const float* __restrict__ Wo,
                                        const unsigned long long* __restrict__ mp,
                                        int sample, int col, float a) {
  unsigned long long ring[8];
#pragma unroll
  for (int q = 0; q < 8; ++q) ring[q] = mp[q * NB + sample];
  int w = -1;
  unsigned long long cur = 0ULL;
  int kA = -1;
  while (true) {
    if (cur == 0ULL) {
      ++w; if (w >= NW) return a;
      cur = ring[w & 7];
      int wn = w + 8; if (wn < NW) ring[w & 7] = mp[wn * NB + sample];
      continue;
    }
    kA = (w << 6) + __builtin_ctzll(cur); cur &= cur - 1; break;
  }
  float vA = Wo[(size_t)kA * 64 + col];
  while (true) {
    int kB = -1;
    while (true) {
      if (cur == 0ULL) {
        ++w; if (w >= NW) break;
        cur = ring[w & 7];
        int wn = w + 8; if (wn < NW) ring[w & 7] = mp[wn * NB + sample];
        continue;
      }
      kB = (w << 6) + __builtin_ctzll(cur); cur &= cur - 1; break;
    }
    float vB = 0.0f;
    if (kB >= 0) vB = Wo[(size_t)kB * 64 + col];
    a += vA;
    if (kB < 0) return a;
    vA = vB;
  }
}

__global__ __launch_bounds__(THREADS) void rsnn_coop(
    const float* __restrict__ state, const float* __restrict__ target,
    const float* __restrict__ Wi, const float* __restrict__ bi,
    const float* __restrict__ Vr, const float* __restrict__ Wf,
    const float* __restrict__ bf, const float* __restrict__ Wo,
    const float* __restrict__ bo, float* __restrict__ out,
    char* __restrict__ wsb) {
  __shared__ float Vr_s[HD * C];          // 64 KB
  __shared__ float Wf_s[HD * C];          // 64 KB
  __shared__ float xk[NB * (KS + 1)];     // 18 KB (pad 9 to dodge bank conflicts)
  __shared__ float Wi_s[128 * C];         // 4 KB

  uint8_t* m1B = (uint8_t*)(wsb + OFF_M1B);
  uint8_t* m2B = (uint8_t*)(wsb + OFF_M2B);
  unsigned long long* m1W = (unsigned long long*)(wsb + OFF_M1W);
  unsigned long long* m2W = (unsigned long long*)(wsb + OFF_M2W);
  unsigned* bcnt = (unsigned*)(wsb + OFF_CNT);
  unsigned* bgen = (unsigned*)(wsb + OFF_GEN);

  const int j = blockIdx.x;       // column-group owner
  const int tid = threadIdx.x;    // = sample index in gather phases
  const int c0 = j * C;

  // stage weight column-slices into LDS
  for (int idx = tid; idx < HD * C; idx += THREADS) {
    int k = idx >> 3, c = idx & 7;
    Vr_s[idx] = Vr[(size_t)k * HD + c0 + c];
    Wf_s[idx] = Wf[(size_t)k * HD + c0 + c];
  }
  for (int idx = tid; idx < 128 * C; idx += THREADS) {
    int k = idx >> 3, c = idx & 7;
    Wi_s[idx] = Wi[(size_t)k * HD + c0 + c];
  }

  // per-thread (= per-sample) state for this block's 8 columns
  float syn1r[C], mem1r[C], syn2r[C], mem2r[C];
#pragma unroll
  for (int c = 0; c < C; ++c) { syn1r[c] = 0.f; mem1r[c] = 0.f; syn2r[c] = 0.f; mem2r[c] = 0.f; }
  unsigned s1own = 0u, s2own = 0u;
  float bir[C], bf2[C];
#pragma unroll
  for (int c = 0; c < C; ++c) { bir[c] = bi[c0 + c]; bf2[c] = bf[c0 + c]; }
  float xwreg[C];

  // readout role: blocks 64..127, 8 samples each, thread = (sample, col)
  const bool isRead = (j >= 64 && j < 128);
  const int rsample = isRead ? ((j - 64) * 8 + (tid >> 6)) : 0;
  const int rcol = tid & 63;
  const float bor = bo[rcol];
  float synr_ = 0.f, memr_ = 0.f, roprev_ = 0.f;

  const float dm = 0.8187307530779818f;
  const float ds = 0.6065306597126334f;
  const float sm = 0.18126924692201818f;

  __syncthreads();

  for (int s = 0; s < NSTEPS; ++s) {
    const int ts = s >> 1;

    // ---- xw = bi + x(ts) @ Wi for own columns (even micro-steps only) ----
    if ((s & 1) == 0) {
#pragma unroll
      for (int c = 0; c < C; ++c) xwreg[c] = bir[c];
      for (int kc = 0; kc < 128; kc += KS) {
        __syncthreads();  // previous chunk fully consumed
#pragma unroll
        for (int idx = tid; idx < NB * KS; idx += THREADS) {
          int i = idx >> 3, kk = idx & 7;
          int k = kc + kk;
          float v = (k < 64) ? state[((size_t)ts * NB + i) * 64 + k]
                             : target[((size_t)ts * NB + i) * 64 + (k - 64)];
          xk[i * (KS + 1) + kk] = v;
        }
        __syncthreads();
#pragma unroll
        for (int kk = 0; kk < KS; ++kk) {
          float xv = xk[tid * (KS + 1) + kk];
#pragma unroll
          for (int c = 0; c < C; ++c)
            xwreg[c] = fmaf(xv, Wi_s[(kc + kk) * C + c], xwreg[c]);
        }
      }
    }

    // ---- layer 1: I1 = xw + s1_prev @ Vr (own cols, all via LDS) ----
    float acc[C];
#pragma unroll
    for (int c = 0; c < C; ++c) acc[c] = xwreg[c];
    gather8(Vr_s, m1W, tid, acc);

    unsigned nb1 = 0u;
#pragma unroll
    for (int c = 0; c < C; ++c) {
      float so = (float)((s1own >> c) & 1u);
      float nmem = (dm * mem1r[c] + sm * syn1r[c]) * (1.0f - so);
      float nsyn = ds * syn1r[c] + acc[c];
      mem1r[c] = nmem; syn1r[c] = nsyn;
      if ((nmem - 1.0f) > 0.0f) nb1 |= (1u << c);
    }
    s1own = nb1;
    m1B[j * NB + tid] = (uint8_t)nb1;

    gridbar(bcnt, bgen);   // B1: mask bytes visible

    // crews: pack bytes -> words (block w<32: m1; 32..63: m2 from last step)
    if (j < 32) {
      unsigned long long v = 0ULL;
#pragma unroll
      for (int b = 0; b < 8; ++b)
        v |= (unsigned long long)m1B[(j * 8 + b) * NB + tid] << (8 * b);
      m1W[j * NB + tid] = v;
    } else if (j < 64) {
      int w = j - 32;
      unsigned long long v = 0ULL;
#pragma unroll
      for (int b = 0; b < 8; ++b)
        v |= (unsigned long long)m2B[(w * 8 + b) * NB + tid] << (8 * b);
      m2W[w * NB + tid] = v;
    }

    gridbar(bcnt, bgen);   // B0: packed words visible

    // ---- layer 2: I2 = bf + ns1 @ Wf ----
    float acc2[C];
#pragma unroll
    for (int c = 0; c < C; ++c) acc2[c] = bf2[c];
    gather8(Wf_s, m1W, tid, acc2);

    unsigned nb2 = 0u;
#pragma unroll
    for (int c = 0; c < C; ++c) {
      float so = (float)((s2own >> c) & 1u);
      float nmem = (dm * mem2r[c] + sm * syn2r[c]) * (1.0f - so);
      float nsyn = ds * syn2r[c] + acc2[c];
      mem2r[c] = nmem; syn2r[c] = nsyn;
      if ((nmem - 1.0f) > 0.0f) nb2 |= (1u << c);
    }
    s2own = nb2;
    m2B[j * NB + tid] = (uint8_t)nb2;

    // ---- delayed readout of step s-1 (m2W holds bits2(s-1)) ----
    if (isRead && s > 0) {
      const int sp = s - 1;
      float a = rowalk(Wo, m2W, rsample, rcol, bor);
      float nmemr = dm * memr_ + sm * synr_;
      float nsynr = ds * synr_ + a;
      memr_ = nmemr; synr_ = nsynr;
      if (sp & 1) {
        int t = sp >> 1;
        float v = 0.5f * (roprev_ + nmemr);
        size_t base = ((size_t)t * NB + rsample) * 32;
        if (rcol < 32) out[base + rcol] = v;
        else out[(size_t)64 * NB * 32 + base + (rcol - 32)] = v;
      } else {
        roprev_ = nmemr;
      }
    }
  }

  // ---- tail: readout(127) ----
  gridbar(bcnt, bgen);
  if (j >= 32 && j < 64) {
    int w = j - 32;
    unsigned long long v = 0ULL;
#pragma unroll
    for (int b = 0; b < 8; ++b)
      v |= (unsigned long long)m2B[(w * 8 + b) * NB + tid] << (8 * b);
    m2W[w * NB + tid] = v;
  }
  gridbar(bcnt, bgen);
  if (isRead) {
    const int sp = NSTEPS - 1;   // 127, odd
    float a = rowalk(Wo, m2W, rsample, rcol, bor);
    float nmemr = dm * memr_ + sm * synr_;
    float v = 0.5f * (roprev_ + nmemr);
    int t = sp >> 1;
    size_t base = ((size_t)t * NB + rsample) * 32;
    if (rcol < 32) out[base + rcol] = v;
    else out[(size_t)64 * NB * 32 + base + (rcol - 32)] = v;
  }
}

extern "C" void kernel_launch(void* const* d_in, const int* in_sizes, int n_in,
                              void* d_out, int out_size, void* d_ws, size_t ws_size,
                              hipStream_t stream) {
  const float* state  = (const float*)d_in[0];
  const float* target = (const float*)d_in[1];
  const float* Wi     = (const float*)d_in[2];
  const float* bi     = (const float*)d_in[3];
  const float* Vr     = (const float*)d_in[4];
  const float* Wf     = (const float*)d_in[5];
  const float* bf     = (const float*)d_in[6];
  const float* Wo     = (const float*)d_in[7];
  const float* bo     = (const float*)d_in[8];
  float* out = (float*)d_out;
  char* wsb = (char*)d_ws;

  init_ws_kernel<<<64, 256, 0, stream>>>(
      (unsigned long long*)(wsb + OFF_M1W),
      (unsigned*)(wsb + OFF_CNT), (unsigned*)(wsb + OFF_GEN));

  void* args[] = {(void*)&state, (void*)&target, (void*)&Wi, (void*)&bi,
                  (void*)&Vr, (void*)&Wf, (void*)&bf, (void*)&Wo, (void*)&bo,
                  (void*)&out, (void*)&wsb};
  hipLaunchCooperativeKernel(rsnn_coop, dim3(NBLK), dim3(THREADS), args, 0, stream);
}

// Round 4
// 5378.773 us; speedup vs baseline: 5.5547x; 5.5547x over previous
//
#include <hip/hip_runtime.h>
#include <stdint.h>

// PolicyNetRSNNPB R4: physical-XCD column sharding, weights L2-resident.
//  - 256 coop blocks (1/CU, forced by 139KB LDS). Block reads HW_REG_XCC_ID,
//    claims rank via per-XCD atomic counter: owns cols [xcd*256,+256) (Vr+Wf
//    slices = 4MB = that XCD's L2) x samples [rank*16,+16).
//  - Wave owns 2 samples, lane owns 4 cols. Spike gather: wave-uniform mask
//    walk -> LDS index list -> batched x8 dwordx4 L2 loads, ascending-k adds
//    (bit-exact vs R1 which scored absmax 0.0). No runtime-indexed reg arrays
//    (R3's scratch disaster, rule #20), no divergent walk, no LDS conflicts.
//  - Sync: per-sample-group 8-block rendezvous (monotonic flag, release add,
//    RELAXED spin -> no L2 invalidation -> weights stay resident). Masks via
//    agent-scope relaxed atomics (sc1 write-through, L2-bypassing).
//  - m2 masks -> 16MB history (nontemporal); readout fully deferred past one
//    final rendezvous (acquire). Halves in-loop sync.

typedef unsigned long long u64;
typedef unsigned int u32;

#define NB 512
#define HD 2048
#define NSTEPS 128
#define THREADS 512
#define NBLK 256
#define COLS 256
#define SPB 16
#define NWPS 32

#define DMc 0.8187307530779818f
#define DSc 0.6065306597126334f
#define SMc 0.18126924692201818f

// ---- ws layout ----
#define OFF_M1W 0
#define SZ_M1W (2 * NB * NWPS * 8)              // 256 KB (double-buffered m1)
#define OFF_M2H (OFF_M1W + SZ_M1W)
#define SZ_M2H ((size_t)NSTEPS * NB * NWPS * 8) // 16 MB (m2 history)
#define OFF_FLAG (OFF_M2H + SZ_M2H)
#define SZ_FLAG (32 * 32 * 4)                   // flag per group, 128B stride
#define OFF_CNT (OFF_FLAG + SZ_FLAG)            // u32[8] xcd rank counters
#define OFF_DONE (OFF_CNT + 64)                 // u32 done counter

#define HWREG_XCC_ID (20 | ((4 - 1) << 11))     // id=20, offset=0, size=4

__global__ void init_ws(u64* __restrict__ m1W, u32* __restrict__ flags,
                        u32* __restrict__ cnt, u32* __restrict__ done) {
  int i = blockIdx.x * 256 + threadIdx.x;
  if (i < 2 * NB * NWPS) m1W[i] = 0ULL;
  if (i < 32 * 32) flags[i] = 0u;
  if (i < 8) cnt[i] = 0u;
  if (i == 0) *done = 0u;
}

// bit i of low-16 -> bit 4i
__device__ __forceinline__ u64 spread4(u64 x) {
  x &= 0xffffULL;
  x = (x | (x << 24)) & 0x000000FF000000FFULL;
  x = (x | (x << 12)) & 0x000F000F000F000FULL;
  x = (x | (x << 6))  & 0x0303030303030303ULL;
  x = (x | (x << 3))  & 0x1111111111111111ULL;
  return x;
}

// Build ascending spike-index list in LDS from 32 mask words (lane-parallel:
// lane i<32 loads word i, wave prefix-scan, scatter). Returns count (uniform).
template <bool ATOMIC>
__device__ __forceinline__ int build_list(const u64* __restrict__ mwords,
                                          uint16_t* __restrict__ lstw, int lane) {
  u64 w = 0ULL;
  if (lane < NWPS) {
    if (ATOMIC)
      w = __hip_atomic_load((u64*)&mwords[lane], __ATOMIC_RELAXED,
                            __HIP_MEMORY_SCOPE_AGENT);
    else
      w = mwords[lane];
  }
  int pc = __popcll(w);
  int pre = pc;
#pragma unroll
  for (int off = 1; off < 64; off <<= 1) {
    int v = __shfl_up(pre, off);
    if (lane >= off) pre += v;
  }
  int excl = pre - pc;
  int total = __shfl(pre, 63);
  int kb = lane << 6;
  while (w) {
    int b = __builtin_ctzll(w);
    w &= w - 1;
    lstw[excl++] = (uint16_t)(kb + b);
  }
  asm volatile("s_waitcnt lgkmcnt(0)" ::: "memory");
  return total;
}

// acc init -> += W rows (ascending k, 8-deep pipelined) -> LIF update.
__device__ __forceinline__ void gather_lif(const float* __restrict__ Wbase,
                                           const uint16_t* __restrict__ lstw,
                                           int total, const float init0,
                                           const float init1, const float init2,
                                           const float init3, float syn[4],
                                           float mem[4], u32& snib) {
  float a0 = init0, a1 = init1, a2 = init2, a3 = init3;
  for (int j0 = 0; j0 < total; j0 += 8) {
    int got = total - j0;
    got = got > 8 ? 8 : got;
    int kk[8];
    float4 v[8];
#pragma unroll
    for (int u = 0; u < 8; ++u) kk[u] = lstw[j0 + (u < got ? u : 0)];
#pragma unroll
    for (int u = 0; u < 8; ++u)
      v[u] = *(const float4*)(Wbase + ((size_t)kk[u] << 11));
#pragma unroll
    for (int u = 0; u < 8; ++u)
      if (u < got) { a0 += v[u].x; a1 += v[u].y; a2 += v[u].z; a3 += v[u].w; }
  }
  float aj[4] = {a0, a1, a2, a3};
  u32 nib = 0;
#pragma unroll
  for (int j = 0; j < 4; ++j) {
    float so = (float)((snib >> j) & 1u);
    float nmem = (DMc * mem[j] + SMc * syn[j]) * (1.0f - so);  // R1 shape
    float nsyn = DSc * syn[j] + aj[j];                          // R1 shape
    mem[j] = nmem;
    syn[j] = nsyn;
    if ((nmem - 1.0f) > 0.0f) nib |= (1u << j);
  }
  snib = nib;
}

__device__ __forceinline__ u64 pack_word(u64 B0, u64 B1, u64 B2, u64 B3, int q) {
  int sh = q * 16;
  return spread4(B0 >> sh) | (spread4(B1 >> sh) << 1) |
         (spread4(B2 >> sh) << 2) | (spread4(B3 >> sh) << 3);
}

__global__ __launch_bounds__(THREADS) void rsnn_coop(
    const float* __restrict__ state, const float* __restrict__ target,
    const float* __restrict__ Wi, const float* __restrict__ bi,
    const float* __restrict__ Vr, const float* __restrict__ Wf,
    const float* __restrict__ bf, const float* __restrict__ Wo,
    const float* __restrict__ bo, float* __restrict__ out,
    char* __restrict__ wsb) {
  __shared__ float Wi_s[128 * COLS];   // 128 KB
  __shared__ uint16_t lst[8][512];     // 8 KB spike lists, per wave
  __shared__ int sh_xcd, sh_rank;

  u64* m1W = (u64*)(wsb + OFF_M1W);
  u64* m2H = (u64*)(wsb + OFF_M2H);
  u32* flags = (u32*)(wsb + OFF_FLAG);
  u32* cnt = (u32*)(wsb + OFF_CNT);
  u32* done = (u32*)(wsb + OFF_DONE);

  const int tid = threadIdx.x;
  const int wv = tid >> 6;
  const int lane = tid & 63;

  if (tid == 0) {
    int xcd = __builtin_amdgcn_s_getreg(HWREG_XCC_ID) & 7;
    sh_xcd = xcd;
    sh_rank = atomicAdd(&cnt[xcd], 1u) & 31;
  }
  __syncthreads();
  const int xcd = sh_xcd;
  const int g = sh_rank;
  const int c0 = xcd * COLS;
  const int s0 = g * SPB;
  const int sA = s0 + wv * 2, sB = sA + 1;

  // stage Wi column slice (this XCD's 256 cols) into LDS
  for (int i = tid; i < 128 * COLS; i += THREADS) {
    int k = i >> 8, c = i & 255;
    Wi_s[i] = Wi[(size_t)k * HD + c0 + c];
  }

  float bir[4], bfr[4];
#pragma unroll
  for (int j = 0; j < 4; ++j) {
    bir[j] = bi[c0 + lane * 4 + j];
    bfr[j] = bf[c0 + lane * 4 + j];
  }

  float syn1[2][4], mem1[2][4], syn2[2][4], mem2[2][4];
#pragma unroll
  for (int r = 0; r < 2; ++r)
#pragma unroll
    for (int j = 0; j < 4; ++j) {
      syn1[r][j] = 0.f; mem1[r][j] = 0.f; syn2[r][j] = 0.f; mem2[r][j] = 0.f;
    }
  u32 s1nib[2] = {0u, 0u}, s2nib[2] = {0u, 0u};
  float xwA[4], xwB[4];

  const float* VrB = Vr + c0 + lane * 4;
  const float* WfB = Wf + c0 + lane * 4;
  u32* myflag = &flags[g * 32];

  __syncthreads();  // Wi_s ready

  for (int s = 0; s < NSTEPS; ++s) {
    const int t = s >> 1;

    // ---- xw = bi + x(t) @ Wi (ascending k, fmaf; Wi from LDS, x from L2) ----
    if ((s & 1) == 0) {
#pragma unroll
      for (int j = 0; j < 4; ++j) { xwA[j] = bir[j]; xwB[j] = bir[j]; }
#pragma unroll
      for (int half = 0; half < 2; ++half) {
        const float* pA = (half ? target : state) + ((size_t)t * NB + sA) * 64;
        const float* pB = (half ? target : state) + ((size_t)t * NB + sB) * 64;
        for (int q = 0; q < 16; ++q) {
          float4 xa = *(const float4*)(pA + 4 * q);
          float4 xb = *(const float4*)(pB + 4 * q);
          float xav[4] = {xa.x, xa.y, xa.z, xa.w};
          float xbv[4] = {xb.x, xb.y, xb.z, xb.w};
#pragma unroll
          for (int kj = 0; kj < 4; ++kj) {
            const float4 w4 = *(const float4*)&Wi_s[(half * 64 + 4 * q + kj) * COLS + lane * 4];
            xwA[0] = fmaf(xav[kj], w4.x, xwA[0]);
            xwA[1] = fmaf(xav[kj], w4.y, xwA[1]);
            xwA[2] = fmaf(xav[kj], w4.z, xwA[2]);
            xwA[3] = fmaf(xav[kj], w4.w, xwA[3]);
            xwB[0] = fmaf(xbv[kj], w4.x, xwB[0]);
            xwB[1] = fmaf(xbv[kj], w4.y, xwB[1]);
            xwB[2] = fmaf(xbv[kj], w4.z, xwB[2]);
            xwB[3] = fmaf(xbv[kj], w4.w, xwB[3]);
          }
        }
      }
    }

    const u64* m1prev = m1W + (size_t)((s + 1) & 1) * NB * NWPS;
    u64* m1cur = m1W + (size_t)(s & 1) * NB * NWPS;

    // ---- layer 1: I1 = xw + s1_prev @ Vr ----
#pragma unroll
    for (int r = 0; r < 2; ++r) {
      const int smp = r ? sB : sA;
      int total = build_list<true>(m1prev + (size_t)smp * NWPS, &lst[wv][0], lane);
      if (r == 0)
        gather_lif(VrB, &lst[wv][0], total, xwA[0], xwA[1], xwA[2], xwA[3],
                   syn1[0], mem1[0], s1nib[0]);
      else
        gather_lif(VrB, &lst[wv][0], total, xwB[0], xwB[1], xwB[2], xwB[3],
                   syn1[1], mem1[1], s1nib[1]);
      u64 B0 = __ballot(s1nib[r] & 1u), B1 = __ballot(s1nib[r] & 2u);
      u64 B2 = __ballot(s1nib[r] & 4u), B3 = __ballot(s1nib[r] & 8u);
      if (lane < 4) {
        u64 wd = pack_word(B0, B1, B2, B3, lane);
        __hip_atomic_store(&m1cur[(size_t)smp * NWPS + 4 * xcd + lane], wd,
                           __ATOMIC_RELAXED, __HIP_MEMORY_SCOPE_AGENT);
      }
    }

    // ---- rendezvous: new m1 visible among the 8 sibling blocks ----
    __syncthreads();  // all waves' mask stores drained (vmcnt 0)
    if (tid == 0) {
      __threadfence();  // release: push stores to coherent point (wb, no inv)
      __hip_atomic_fetch_add(myflag, 1u, __ATOMIC_RELEASE,
                             __HIP_MEMORY_SCOPE_AGENT);
      u32 tgt = 8u * (u32)(s + 1);
      while (__hip_atomic_load(myflag, __ATOMIC_RELAXED,
                               __HIP_MEMORY_SCOPE_AGENT) < tgt)
        __builtin_amdgcn_s_sleep(1);
    }
    __syncthreads();

    // ---- layer 2: I2 = bf + ns1 @ Wf ; m2 -> history ----
#pragma unroll
    for (int r = 0; r < 2; ++r) {
      const int smp = r ? sB : sA;
      int total = build_list<true>(m1cur + (size_t)smp * NWPS, &lst[wv][0], lane);
      gather_lif(WfB, &lst[wv][0], total, bfr[0], bfr[1], bfr[2], bfr[3],
                 syn2[r], mem2[r], s2nib[r]);
      u64 B0 = __ballot(s2nib[r] & 1u), B1 = __ballot(s2nib[r] & 2u);
      u64 B2 = __ballot(s2nib[r] & 4u), B3 = __ballot(s2nib[r] & 8u);
      if (lane < 4) {
        u64 wd = pack_word(B0, B1, B2, B3, lane);
        __builtin_nontemporal_store(
            wd, &m2H[((size_t)s * NB + smp) * NWPS + 4 * xcd + lane]);
      }
    }
  }

  // ---- final rendezvous: all m2 history visible ----
  __syncthreads();
  if (tid == 0) {
    __threadfence();
    __hip_atomic_fetch_add(done, 1u, __ATOMIC_RELEASE, __HIP_MEMORY_SCOPE_AGENT);
    while (__hip_atomic_load(done, __ATOMIC_RELAXED,
                             __HIP_MEMORY_SCOPE_AGENT) < (u32)NBLK)
      __builtin_amdgcn_s_sleep(1);
    (void)__hip_atomic_load(done, __ATOMIC_ACQUIRE, __HIP_MEMORY_SCOPE_AGENT);
  }
  __syncthreads();

  // ---- deferred readout: wave = one sample, lane = one of 64 cols ----
  const int gw = blockIdx.x * 8 + wv;
  if (gw < NB) {
    const int smp = gw;
    const float bor = bo[lane];
    float synr = 0.f, memr = 0.f, roprev = 0.f;
    for (int s = 0; s < NSTEPS; ++s) {
      int total = build_list<false>(m2H + ((size_t)s * NB + smp) * NWPS,
                                    &lst[wv][0], lane);
      float a = bor;
      for (int j0 = 0; j0 < total; j0 += 8) {
        int got = total - j0;
        got = got > 8 ? 8 : got;
        int kk[8];
        float vv[8];
#pragma unroll
        for (int u = 0; u < 8; ++u) kk[u] = lst[wv][j0 + (u < got ? u : 0)];
#pragma unroll
        for (int u = 0; u < 8; ++u) vv[u] = Wo[((size_t)kk[u] << 6) + lane];
#pragma unroll
        for (int u = 0; u < 8; ++u)
          if (u < got) a += vv[u];
      }
      float nmemr = DMc * memr + SMc * synr;  // R1 shape
      float nsynr = DSc * synr + a;           // R1 shape
      memr = nmemr;
      synr = nsynr;
      if (s & 1) {
        float v = 0.5f * (roprev + nmemr);
        size_t base = ((size_t)(s >> 1) * NB + smp) * 32;
        if (lane < 32) out[base + lane] = v;
        else out[(size_t)64 * NB * 32 + base + (lane - 32)] = v;
      } else {
        roprev = nmemr;
      }
    }
  }
}

extern "C" void kernel_launch(void* const* d_in, const int* in_sizes, int n_in,
                              void* d_out, int out_size, void* d_ws, size_t ws_size,
                              hipStream_t stream) {
  const float* state  = (const float*)d_in[0];
  const float* target = (const float*)d_in[1];
  const float* Wi     = (const float*)d_in[2];
  const float* bi     = (const float*)d_in[3];
  const float* Vr     = (const float*)d_in[4];
  const float* Wf     = (const float*)d_in[5];
  const float* bf     = (const float*)d_in[6];
  const float* Wo     = (const float*)d_in[7];
  const float* bo     = (const float*)d_in[8];
  float* out = (float*)d_out;
  char* wsb = (char*)d_ws;

  init_ws<<<128, 256, 0, stream>>>((u64*)(wsb + OFF_M1W), (u32*)(wsb + OFF_FLAG),
                                   (u32*)(wsb + OFF_CNT), (u32*)(wsb + OFF_DONE));

  void* args[] = {(void*)&state, (void*)&target, (void*)&Wi, (void*)&bi,
                  (void*)&Vr, (void*)&Wf, (void*)&bf, (void*)&Wo, (void*)&bo,
                  (void*)&out, (void*)&wsb};
  hipLaunchCooperativeKernel(rsnn_coop, dim3(NBLK), dim3(THREADS), args, 0, stream);
}

// Round 5
// 4195.742 us; speedup vs baseline: 7.1209x; 1.2820x over previous
//
#include <hip/hip_runtime.h>
#include <stdint.h>

// PolicyNetRSNNPB R5 = R4 minus in-loop cache-maintenance fences.
// R4 finding: per-step __threadfence() (agent acq-rel) emits buffer_inv +
// buffer_wbl2 -> drops all clean L2 lines (the weights!) every step ->
// 19.5 MB/step HBM re-fetch = 44 us/step = the whole 5.6 ms.
// R5: all cross-block data moves via sc1 (MALL-routed) atomics, so in-loop
// ordering needs only __syncthreads' vmcnt(0) drain + relaxed agent atomics.
// Zero cache-maintenance ops in the loop; one final __threadfence before the
// deferred readout (graph-replay staleness). Bit-exact order preserved.

typedef unsigned long long u64;
typedef unsigned int u32;

#define NB 512
#define HD 2048
#define NSTEPS 128
#define THREADS 512
#define NBLK 256
#define COLS 256
#define SPB 16
#define NWPS 32

#define DMc 0.8187307530779818f
#define DSc 0.6065306597126334f
#define SMc 0.18126924692201818f

// ---- ws layout ----
#define OFF_M1W 0
#define SZ_M1W (2 * NB * NWPS * 8)              // 256 KB (double-buffered m1)
#define OFF_M2H (OFF_M1W + SZ_M1W)
#define SZ_M2H ((size_t)NSTEPS * NB * NWPS * 8) // 16 MB (m2 history)
#define OFF_FLAG (OFF_M2H + SZ_M2H)
#define SZ_FLAG (32 * 32 * 4)                   // flag per group, 128B stride
#define OFF_CNT (OFF_FLAG + SZ_FLAG)            // u32[8] xcd rank counters
#define OFF_DONE (OFF_CNT + 64)                 // u32 done counter

#define HWREG_XCC_ID (20 | ((4 - 1) << 11))     // id=20, offset=0, size=4

__global__ void init_ws(u64* __restrict__ m1W, u32* __restrict__ flags,
                        u32* __restrict__ cnt, u32* __restrict__ done) {
  int i = blockIdx.x * 256 + threadIdx.x;
  if (i < 2 * NB * NWPS) m1W[i] = 0ULL;
  if (i < 32 * 32) flags[i] = 0u;
  if (i < 8) cnt[i] = 0u;
  if (i == 0) *done = 0u;
}

// bit i of low-16 -> bit 4i
__device__ __forceinline__ u64 spread4(u64 x) {
  x &= 0xffffULL;
  x = (x | (x << 24)) & 0x000000FF000000FFULL;
  x = (x | (x << 12)) & 0x000F000F000F000FULL;
  x = (x | (x << 6))  & 0x0303030303030303ULL;
  x = (x | (x << 3))  & 0x1111111111111111ULL;
  return x;
}

// Build ascending spike-index list in LDS from 32 mask words (lane-parallel:
// lane i<32 loads word i, wave prefix-scan, scatter). Returns count (uniform).
template <bool ATOMIC>
__device__ __forceinline__ int build_list(const u64* __restrict__ mwords,
                                          uint16_t* __restrict__ lstw, int lane) {
  u64 w = 0ULL;
  if (lane < NWPS) {
    if (ATOMIC)
      w = __hip_atomic_load((u64*)&mwords[lane], __ATOMIC_RELAXED,
                            __HIP_MEMORY_SCOPE_AGENT);
    else
      w = mwords[lane];
  }
  int pc = __popcll(w);
  int pre = pc;
#pragma unroll
  for (int off = 1; off < 64; off <<= 1) {
    int v = __shfl_up(pre, off);
    if (lane >= off) pre += v;
  }
  int excl = pre - pc;
  int total = __shfl(pre, 63);
  int kb = lane << 6;
  while (w) {
    int b = __builtin_ctzll(w);
    w &= w - 1;
    lstw[excl++] = (uint16_t)(kb + b);
  }
  asm volatile("s_waitcnt lgkmcnt(0)" ::: "memory");
  return total;
}

// acc init -> += W rows (ascending k, 8-deep pipelined) -> LIF update.
__device__ __forceinline__ void gather_lif(const float* __restrict__ Wbase,
                                           const uint16_t* __restrict__ lstw,
                                           int total, const float init0,
                                           const float init1, const float init2,
                                           const float init3, float syn[4],
                                           float mem[4], u32& snib) {
  float a0 = init0, a1 = init1, a2 = init2, a3 = init3;
  for (int j0 = 0; j0 < total; j0 += 8) {
    int got = total - j0;
    got = got > 8 ? 8 : got;
    int kk[8];
    float4 v[8];
#pragma unroll
    for (int u = 0; u < 8; ++u) kk[u] = lstw[j0 + (u < got ? u : 0)];
#pragma unroll
    for (int u = 0; u < 8; ++u)
      v[u] = *(const float4*)(Wbase + ((size_t)kk[u] << 11));
#pragma unroll
    for (int u = 0; u < 8; ++u)
      if (u < got) { a0 += v[u].x; a1 += v[u].y; a2 += v[u].z; a3 += v[u].w; }
  }
  float aj[4] = {a0, a1, a2, a3};
  u32 nib = 0;
#pragma unroll
  for (int j = 0; j < 4; ++j) {
    float so = (float)((snib >> j) & 1u);
    float nmem = (DMc * mem[j] + SMc * syn[j]) * (1.0f - so);  // R1 shape
    float nsyn = DSc * syn[j] + aj[j];                          // R1 shape
    mem[j] = nmem;
    syn[j] = nsyn;
    if ((nmem - 1.0f) > 0.0f) nib |= (1u << j);
  }
  snib = nib;
}

__device__ __forceinline__ u64 pack_word(u64 B0, u64 B1, u64 B2, u64 B3, int q) {
  int sh = q * 16;
  return spread4(B0 >> sh) | (spread4(B1 >> sh) << 1) |
         (spread4(B2 >> sh) << 2) | (spread4(B3 >> sh) << 3);
}

__global__ __launch_bounds__(THREADS) void rsnn_coop(
    const float* __restrict__ state, const float* __restrict__ target,
    const float* __restrict__ Wi, const float* __restrict__ bi,
    const float* __restrict__ Vr, const float* __restrict__ Wf,
    const float* __restrict__ bf, const float* __restrict__ Wo,
    const float* __restrict__ bo, float* __restrict__ out,
    char* __restrict__ wsb) {
  __shared__ float Wi_s[128 * COLS];   // 128 KB
  __shared__ uint16_t lst[8][512];     // 8 KB spike lists, per wave
  __shared__ int sh_xcd, sh_rank;

  u64* m1W = (u64*)(wsb + OFF_M1W);
  u64* m2H = (u64*)(wsb + OFF_M2H);
  u32* flags = (u32*)(wsb + OFF_FLAG);
  u32* cnt = (u32*)(wsb + OFF_CNT);
  u32* done = (u32*)(wsb + OFF_DONE);

  const int tid = threadIdx.x;
  const int wv = tid >> 6;
  const int lane = tid & 63;

  if (tid == 0) {
    int xcd = __builtin_amdgcn_s_getreg(HWREG_XCC_ID) & 7;
    sh_xcd = xcd;
    sh_rank = atomicAdd(&cnt[xcd], 1u) & 31;
  }
  __syncthreads();
  const int xcd = sh_xcd;
  const int g = sh_rank;
  const int c0 = xcd * COLS;
  const int s0 = g * SPB;
  const int sA = s0 + wv * 2, sB = sA + 1;

  // stage Wi column slice (this XCD's 256 cols) into LDS
  for (int i = tid; i < 128 * COLS; i += THREADS) {
    int k = i >> 8, c = i & 255;
    Wi_s[i] = Wi[(size_t)k * HD + c0 + c];
  }

  float bir[4], bfr[4];
#pragma unroll
  for (int j = 0; j < 4; ++j) {
    bir[j] = bi[c0 + lane * 4 + j];
    bfr[j] = bf[c0 + lane * 4 + j];
  }

  float syn1[2][4], mem1[2][4], syn2[2][4], mem2[2][4];
#pragma unroll
  for (int r = 0; r < 2; ++r)
#pragma unroll
    for (int j = 0; j < 4; ++j) {
      syn1[r][j] = 0.f; mem1[r][j] = 0.f; syn2[r][j] = 0.f; mem2[r][j] = 0.f;
    }
  u32 s1nib[2] = {0u, 0u}, s2nib[2] = {0u, 0u};
  float xwA[4], xwB[4];

  const float* VrB = Vr + c0 + lane * 4;
  const float* WfB = Wf + c0 + lane * 4;
  u32* myflag = &flags[g * 32];

  __syncthreads();  // Wi_s ready

  for (int s = 0; s < NSTEPS; ++s) {
    const int t = s >> 1;

    // ---- xw = bi + x(t) @ Wi (ascending k, fmaf; Wi from LDS, x from L2) ----
    if ((s & 1) == 0) {
#pragma unroll
      for (int j = 0; j < 4; ++j) { xwA[j] = bir[j]; xwB[j] = bir[j]; }
#pragma unroll
      for (int half = 0; half < 2; ++half) {
        const float* pA = (half ? target : state) + ((size_t)t * NB + sA) * 64;
        const float* pB = (half ? target : state) + ((size_t)t * NB + sB) * 64;
        for (int q = 0; q < 16; ++q) {
          float4 xa = *(const float4*)(pA + 4 * q);
          float4 xb = *(const float4*)(pB + 4 * q);
          float xav[4] = {xa.x, xa.y, xa.z, xa.w};
          float xbv[4] = {xb.x, xb.y, xb.z, xb.w};
#pragma unroll
          for (int kj = 0; kj < 4; ++kj) {
            const float4 w4 = *(const float4*)&Wi_s[(half * 64 + 4 * q + kj) * COLS + lane * 4];
            xwA[0] = fmaf(xav[kj], w4.x, xwA[0]);
            xwA[1] = fmaf(xav[kj], w4.y, xwA[1]);
            xwA[2] = fmaf(xav[kj], w4.z, xwA[2]);
            xwA[3] = fmaf(xav[kj], w4.w, xwA[3]);
            xwB[0] = fmaf(xbv[kj], w4.x, xwB[0]);
            xwB[1] = fmaf(xbv[kj], w4.y, xwB[1]);
            xwB[2] = fmaf(xbv[kj], w4.z, xwB[2]);
            xwB[3] = fmaf(xbv[kj], w4.w, xwB[3]);
          }
        }
      }
    }

    const u64* m1prev = m1W + (size_t)((s + 1) & 1) * NB * NWPS;
    u64* m1cur = m1W + (size_t)(s & 1) * NB * NWPS;

    // ---- layer 1: I1 = xw + s1_prev @ Vr ----
#pragma unroll
    for (int r = 0; r < 2; ++r) {
      const int smp = r ? sB : sA;
      int total = build_list<true>(m1prev + (size_t)smp * NWPS, &lst[wv][0], lane);
      if (r == 0)
        gather_lif(VrB, &lst[wv][0], total, xwA[0], xwA[1], xwA[2], xwA[3],
                   syn1[0], mem1[0], s1nib[0]);
      else
        gather_lif(VrB, &lst[wv][0], total, xwB[0], xwB[1], xwB[2], xwB[3],
                   syn1[1], mem1[1], s1nib[1]);
      u64 B0 = __ballot(s1nib[r] & 1u), B1 = __ballot(s1nib[r] & 2u);
      u64 B2 = __ballot(s1nib[r] & 4u), B3 = __ballot(s1nib[r] & 8u);
      if (lane < 4) {
        u64 wd = pack_word(B0, B1, B2, B3, lane);
        __hip_atomic_store(&m1cur[(size_t)smp * NWPS + 4 * xcd + lane], wd,
                           __ATOMIC_RELAXED, __HIP_MEMORY_SCOPE_AGENT);
      }
    }

    // ---- rendezvous: new m1 visible among the 8 sibling blocks ----
    // NO cache-maintenance here: sc1 atomics are MALL-routed; __syncthreads
    // drains vmcnt(0) per wave before the barrier, so all mask stores are
    // complete at the coherent point before tid0's flag increment.
    __syncthreads();
    if (tid == 0) {
      __hip_atomic_fetch_add(myflag, 1u, __ATOMIC_RELAXED,
                             __HIP_MEMORY_SCOPE_AGENT);
      u32 tgt = 8u * (u32)(s + 1);
      while (__hip_atomic_load(myflag, __ATOMIC_RELAXED,
                               __HIP_MEMORY_SCOPE_AGENT) < tgt)
        __builtin_amdgcn_s_sleep(1);
    }
    __syncthreads();

    // ---- layer 2: I2 = bf + ns1 @ Wf ; m2 -> history (sc1, never dirty) ----
#pragma unroll
    for (int r = 0; r < 2; ++r) {
      const int smp = r ? sB : sA;
      int total = build_list<true>(m1cur + (size_t)smp * NWPS, &lst[wv][0], lane);
      gather_lif(WfB, &lst[wv][0], total, bfr[0], bfr[1], bfr[2], bfr[3],
                 syn2[r], mem2[r], s2nib[r]);
      u64 B0 = __ballot(s2nib[r] & 1u), B1 = __ballot(s2nib[r] & 2u);
      u64 B2 = __ballot(s2nib[r] & 4u), B3 = __ballot(s2nib[r] & 8u);
      if (lane < 4) {
        u64 wd = pack_word(B0, B1, B2, B3, lane);
        __hip_atomic_store(&m2H[((size_t)s * NB + smp) * NWPS + 4 * xcd + lane],
                           wd, __ATOMIC_RELAXED, __HIP_MEMORY_SCOPE_AGENT);
      }
    }
  }

  // ---- final rendezvous: all m2 history visible to plain loads ----
  // Keep the full fence ONCE: buffer_inv drops replay-stale m2H lines from
  // this block's L2 before the plain-load readout (graph replays reuse cache).
  __syncthreads();
  if (tid == 0) {
    __threadfence();
    __hip_atomic_fetch_add(done, 1u, __ATOMIC_RELEASE, __HIP_MEMORY_SCOPE_AGENT);
    while (__hip_atomic_load(done, __ATOMIC_RELAXED,
                             __HIP_MEMORY_SCOPE_AGENT) < (u32)NBLK)
      __builtin_amdgcn_s_sleep(1);
    __threadfence();
  }
  __syncthreads();

  // ---- deferred readout: wave = one sample, lane = one of 64 cols ----
  const int gw = blockIdx.x * 8 + wv;
  if (gw < NB) {
    const int smp = gw;
    const float bor = bo[lane];
    float synr = 0.f, memr = 0.f, roprev = 0.f;
    for (int s = 0; s < NSTEPS; ++s) {
      int total = build_list<false>(m2H + ((size_t)s * NB + smp) * NWPS,
                                    &lst[wv][0], lane);
      float a = bor;
      for (int j0 = 0; j0 < total; j0 += 8) {
        int got = total - j0;
        got = got > 8 ? 8 : got;
        int kk[8];
        float vv[8];
#pragma unroll
        for (int u = 0; u < 8; ++u) kk[u] = lst[wv][j0 + (u < got ? u : 0)];
#pragma unroll
        for (int u = 0; u < 8; ++u) vv[u] = Wo[((size_t)kk[u] << 6) + lane];
#pragma unroll
        for (int u = 0; u < 8; ++u)
          if (u < got) a += vv[u];
      }
      float nmemr = DMc * memr + SMc * synr;  // R1 shape
      float nsynr = DSc * synr + a;           // R1 shape
      memr = nmemr;
      synr = nsynr;
      if (s & 1) {
        float v = 0.5f * (roprev + nmemr);
        size_t base = ((size_t)(s >> 1) * NB + smp) * 32;
        if (lane < 32) out[base + lane] = v;
        else out[(size_t)64 * NB * 32 + base + (lane - 32)] = v;
      } else {
        roprev = nmemr;
      }
    }
  }
}

extern "C" void kernel_launch(void* const* d_in, const int* in_sizes, int n_in,
                              void* d_out, int out_size, void* d_ws, size_t ws_size,
                              hipStream_t stream) {
  const float* state  = (const float*)d_in[0];
  const float* target = (const float*)d_in[1];
  const float* Wi     = (const float*)d_in[2];
  const float* bi     = (const float*)d_in[3];
  const float* Vr     = (const float*)d_in[4];
  const float* Wf     = (const float*)d_in[5];
  const float* bf     = (const float*)d_in[6];
  const float* Wo     = (const float*)d_in[7];
  const float* bo     = (const float*)d_in[8];
  float* out = (float*)d_out;
  char* wsb = (char*)d_ws;

  init_ws<<<128, 256, 0, stream>>>((u64*)(wsb + OFF_M1W), (u32*)(wsb + OFF_FLAG),
                                   (u32*)(wsb + OFF_CNT), (u32*)(wsb + OFF_DONE));

  void* args[] = {(void*)&state, (void*)&target, (void*)&Wi, (void*)&bi,
                  (void*)&Vr, (void*)&Wf, (void*)&bf, (void*)&Wo, (void*)&bo,
                  (void*)&out, (void*)&wsb};
  hipLaunchCooperativeKernel(rsnn_coop, dim3(NBLK), dim3(THREADS), args, 0, stream);
}